// Round 1
// baseline (60.946 us; speedup 1.0000x reference)
//
#include <hip/hip_runtime.h>
#include <hip/hip_bf16.h>

// ws layout (requires ws_size >= 17039360 B):
//   [0, 221184)        : weights as bf16 in MFMA B-fragment order
//   [221184, 221440)   : 256 B of zeros (OOB halo source)
//   [262144, 17039360) : x_t = x transposed to [b][s][c] bf16 (16 MiB)
#define WS_W_OFF    0
#define WS_ZERO_OFF 221184
#define WS_XT_OFF   262144

typedef __attribute__((ext_vector_type(8))) short s16x8;
typedef __attribute__((ext_vector_type(4))) float f32x4;

#define GLOBAL_AS __attribute__((address_space(1)))
#define LDS_AS    __attribute__((address_space(3)))

__device__ __forceinline__ unsigned short f2bf(float f) {
  // round-to-nearest-even bf16 (inputs are normal randoms; no NaN handling needed)
  unsigned u = __builtin_bit_cast(unsigned, f);
  u = u + 0x7fffu + ((u >> 16) & 1u);
  return (unsigned short)(u >> 16);
}

// ---------------------------------------------------------------------------
// Weights: W[cout][cin][tap] fp32 -> bf16 fragments.
// Fragment f = tap*8 + st2*4 + nf holds B[n][k] for n = nf*16 + (lane&15),
// cin = st2*32 + (lane>>4)*8 + j  (16x16x32 MFMA B layout, contiguous-k per lane).
// bf16 index = (f*64 + lane)*8 + j.
__global__ void wt_kernel(const float* __restrict__ w,
                          unsigned short* __restrict__ wsw,
                          float* __restrict__ zeros) {
  int t = blockIdx.x * 256 + threadIdx.x;        // 110592 threads exactly
  int tap  = t % 27;
  int cin  = (t / 27) & 63;
  int cout = t / (27 * 64);
  int st2 = cin >> 5;
  int q   = (cin >> 3) & 3;
  int j   = cin & 7;
  int nf  = cout >> 4;
  int lane = q * 16 + (cout & 15);
  int dst = (((tap * 2 + st2) * 4 + nf) * 64 + lane) * 8 + j;
  wsw[dst] = f2bf(w[t]);
  if (t < 64) zeros[t] = 0.0f;
}

// ---------------------------------------------------------------------------
// x: NCDHW fp32 -> x_t[b][s][c] bf16 (channels-last). Reads coalesced along s.
__global__ void xt_kernel(const float* __restrict__ x,
                          unsigned short* __restrict__ xt) {
  int t  = blockIdx.x * 256 + threadIdx.x;       // 1048576 threads
  int s  = t & 32767;
  int c8 = (t >> 15) & 7;
  int b  = t >> 18;
  const float* src = x + (size_t)(b * 64 + c8 * 8) * 32768 + s;
  s16x8 v;
  #pragma unroll
  for (int k = 0; k < 8; ++k) v[k] = (short)f2bf(src[(size_t)k * 32768]);
  *(s16x8*)(xt + (size_t)(b * 32768 + s) * 64 + c8 * 8) = v;
}

// ---------------------------------------------------------------------------
// Implicit-GEMM conv. Block = (b, z-pair, y-pair): 128 output positions x 64 couts.
// 4 waves; wave w owns (zo=w>>1, yo=w&1): 32 positions (one x-row pair? no: one
// (z,y) row of 32 x) x 64 couts. K-loop: 27 taps x (K=64 as 2 MFMA K-steps).
// A from LDS halo (XOR-swizzled), B from ws in registers (double-buffered).
__global__ __launch_bounds__(256) void conv_kernel(const float* __restrict__ bias,
                                                   float* __restrict__ out,
                                                   const char* __restrict__ ws) {
  __shared__ unsigned char halo[4 * 4 * 34 * 128];   // 69632 B

  const int tid  = threadIdx.x;
  const int lane = tid & 63;
  const int w    = tid >> 6;
  const int bid  = blockIdx.x;
  const int yt = bid & 15, zt = (bid >> 4) & 15, b = bid >> 8;
  const int z0 = zt * 2, y0 = yt * 2;
  const int zo = w >> 1, yo = w & 1;

  // ---- stage halo: 544 positions x 128 B via global_load_lds (16 B/lane) ----
  {
    const int slot = lane & 7;
    const int psub = lane >> 3;
    for (int i = 0; i < 17; ++i) {
      int cb  = (i * 4 + w) * 8;                 // 8 positions per wave-iter
      int pos = cb + psub;
      int hz = pos / 136; int rem = pos - hz * 136;
      int hy = rem / 34;  int hx = rem - hy * 34;
      int gz = z0 + hz - 1, gy = y0 + hy - 1, gx = hx - 1;
      bool inb = ((unsigned)gz < 32u) & ((unsigned)gy < 32u) & ((unsigned)gx < 32u);
      int s = (gz * 32 + gy) * 32 + gx;
      // source-side swizzle so that LDS slot 'slot' holds cin-chunk (slot ^ (hx&7))
      int src = inb ? (WS_XT_OFF + (b * 32768 + s) * 128 + ((slot ^ (hx & 7)) << 4))
                    : WS_ZERO_OFF;
      __builtin_amdgcn_global_load_lds(
          (const GLOBAL_AS void*)(ws + src),
          (LDS_AS void*)(&halo[cb * 128 + (lane << 4)]),
          16, 0, 0);
    }
  }

  const s16x8* __restrict__ wfr = (const s16x8*)(ws + WS_W_OFF);

  f32x4 zero4 = {0.f, 0.f, 0.f, 0.f};
  f32x4 acc[2][4];
  #pragma unroll
  for (int mf = 0; mf < 2; ++mf)
    #pragma unroll
    for (int nf = 0; nf < 4; ++nf) acc[mf][nf] = zero4;

  s16x8 BA[8], BB[8];
  #pragma unroll
  for (int f = 0; f < 8; ++f) BA[f] = wfr[f * 64 + lane];   // tap 0

  __syncthreads();   // drains global_load_lds (vmcnt) + orders halo for all waves

  const int r15 = lane & 15;
  const int hi4 = lane >> 4;

  auto loadB = [&](s16x8* dst, int tap) {
    #pragma unroll
    for (int f = 0; f < 8; ++f) dst[f] = wfr[(tap * 8 + f) * 64 + lane];
  };

  auto compute = [&](int tap, const s16x8* B) {
    int kd = tap / 9;
    int rem9 = tap - kd * 9;
    int kh = rem9 / 3;
    int kw = rem9 - kh * 3;
    int plane = (zo + kd) * 4 + (yo + kh);
    #pragma unroll
    for (int st2 = 0; st2 < 2; ++st2) {
      s16x8 a[2];
      #pragma unroll
      for (int mf = 0; mf < 2; ++mf) {
        int hx   = mf * 16 + r15 + kw;
        int pos  = plane * 34 + hx;
        int slot = (st2 * 4 + hi4) ^ (hx & 7);
        a[mf] = *(const s16x8*)&halo[pos * 128 + slot * 16];
      }
      #pragma unroll
      for (int mf = 0; mf < 2; ++mf)
        #pragma unroll
        for (int nf = 0; nf < 4; ++nf)
          acc[mf][nf] = __builtin_amdgcn_mfma_f32_16x16x32_bf16(
              a[mf], B[st2 * 4 + nf], acc[mf][nf], 0, 0, 0);
    }
  };

  // 27 taps, B double-buffered in registers, static indexing throughout
  for (int t = 0; t < 13; ++t) {
    loadB(BB, 2 * t + 1);
    compute(2 * t, BA);
    loadB(BA, 2 * t + 2);
    compute(2 * t + 1, BB);
  }
  compute(26, BA);

  // ---- epilogue: D row = spatial x (within 16-frag), col = cout ----
  const int z = z0 + zo, y = y0 + yo;
  #pragma unroll
  for (int nf = 0; nf < 4; ++nf) {
    int cout = nf * 16 + r15;
    float bv = bias[cout];
    float* orow = out + ((size_t)((b * 64 + cout) * 32 + z) * 32 + y) * 32;
    #pragma unroll
    for (int mf = 0; mf < 2; ++mf) {
      int x0 = mf * 16 + 4 * hi4;
      f32x4 v;
      #pragma unroll
      for (int r = 0; r < 4; ++r) v[r] = acc[mf][nf][r] + bv;
      *(f32x4*)&orow[x0] = v;
    }
  }
}

extern "C" void kernel_launch(void* const* d_in, const int* in_sizes, int n_in,
                              void* d_out, int out_size, void* d_ws, size_t ws_size,
                              hipStream_t stream) {
  const float* x    = (const float*)d_in[0];
  const float* wgt  = (const float*)d_in[1];
  const float* bias = (const float*)d_in[2];
  float* out = (float*)d_out;
  char* ws = (char*)d_ws;

  wt_kernel<<<432, 256, 0, stream>>>(wgt,
                                     (unsigned short*)(ws + WS_W_OFF),
                                     (float*)(ws + WS_ZERO_OFF));
  xt_kernel<<<4096, 256, 0, stream>>>(x, (unsigned short*)(ws + WS_XT_OFF));
  conv_kernel<<<1024, 256, 0, stream>>>(bias, out, ws);
}